// Round 3
// baseline (175.906 us; speedup 1.0000x reference)
//
#include <hip/hip_runtime.h>
#include <hip/hip_bf16.h>
#include <cstdint>
#include <cstddef>

// Problem constants
#define B_ 8
#define S_ 2048
#define D_ 1024
#define RFAC 32.0f
#define ALPHA 0.2f
#define BETA 0.1f
#define GAMMA 0.1f
// EMA truncation window: 0.8^32 ~ 8e-4 ~ bf16 noise floor (threshold 0.108)
#define KW 32
#define TB 64

typedef float f32x4_t __attribute__((ext_vector_type(4)));
typedef short bf16x8_t __attribute__((ext_vector_type(8)));

__device__ __forceinline__ unsigned short f2bf(float f) {
    unsigned u = __float_as_uint(f);
    u = (u + 0x7fffu + ((u >> 16) & 1u)) >> 16;
    return (unsigned short)u;
}
__device__ __forceinline__ float bf2f(unsigned short h) {
    return __uint_as_float(((unsigned)h) << 16);
}

// ---------------------------------------------------------------------------
// Kernel 1: per-row normalize, pre-scaled by ALPHA, output bf16.
__global__ __launch_bounds__(256) void normalize_k(const float* __restrict__ q,
                                                   const float* __restrict__ k,
                                                   unsigned short* __restrict__ qh,
                                                   unsigned short* __restrict__ kh) {
    int row  = blockIdx.x * 4 + (threadIdx.x >> 6);
    int lane = threadIdx.x & 63;
    const float4* qr = (const float4*)(q + (size_t)row * D_);
    const float4* kr = (const float4*)(k + (size_t)row * D_);
    float4 qa[4], ka[4];
    float sq = 0.f, sk = 0.f;
#pragma unroll
    for (int j = 0; j < 4; ++j) {
        qa[j] = qr[lane + 64 * j];
        ka[j] = kr[lane + 64 * j];
        sq += qa[j].x * qa[j].x + qa[j].y * qa[j].y + qa[j].z * qa[j].z + qa[j].w * qa[j].w;
        sk += ka[j].x * ka[j].x + ka[j].y * ka[j].y + ka[j].z * ka[j].z + ka[j].w * ka[j].w;
    }
#pragma unroll
    for (int off = 32; off > 0; off >>= 1) {
        sq += __shfl_xor(sq, off, 64);
        sk += __shfl_xor(sk, off, 64);
    }
    float rq = ALPHA / (sqrtf(sq) + 1e-6f);
    float rk = ALPHA / (sqrtf(sk) + 1e-6f);
    unsigned short* qo = qh + (size_t)row * D_;
    unsigned short* ko = kh + (size_t)row * D_;
#pragma unroll
    for (int j = 0; j < 4; ++j) {
        ushort4 oq, ok;
        oq.x = f2bf(qa[j].x * rq); oq.y = f2bf(qa[j].y * rq);
        oq.z = f2bf(qa[j].z * rq); oq.w = f2bf(qa[j].w * rq);
        ok.x = f2bf(ka[j].x * rk); ok.y = f2bf(ka[j].y * rk);
        ok.z = f2bf(ka[j].z * rk); ok.w = f2bf(ka[j].w * rk);
        ((ushort4*)qo)[lane + 64 * j] = oq;
        ((ushort4*)ko)[lane + 64 * j] = ok;
    }
}

// ---------------------------------------------------------------------------
// Kernel 2: W -> bf16 convert.
__global__ __launch_bounds__(256) void wconv_k(const float* __restrict__ W,
                                               unsigned short* __restrict__ Wb) {
    int i = blockIdx.x * 256 + threadIdx.x;
    float4 w = ((const float4*)W)[i];
    ushort4 o;
    o.x = f2bf(w.x); o.y = f2bf(w.y); o.z = f2bf(w.z); o.w = f2bf(w.w);
    ((ushort4*)Wb)[i] = o;
}

// ---------------------------------------------------------------------------
// Kernel 3: fused windowed EMA + coef. Block = (b, 64-step chunk), 256 thr
// x 4 d's of u,v state in registers. Per output-t: in-wave butterfly reduce
// of (u.u, v.vv); cross-wave finish after the loop. Vb never materialized.
__global__ __launch_bounds__(256) void ema_coef_k(const unsigned short* __restrict__ qh,
                                                  const unsigned short* __restrict__ kh,
                                                  const float* __restrict__ vv,
                                                  unsigned short* __restrict__ Ub,
                                                  float* __restrict__ coef) {
    __shared__ float sm[TB * 8];   // [t][wave*2 + {uu,sd}]
    const int chunks = S_ / TB;
    int b  = blockIdx.x / chunks;
    int t0 = (blockIdx.x % chunks) * TB;
    int ts = t0 - KW; if (ts < 0) ts = 0;
    int tid = threadIdx.x;
    int lane = tid & 63, wave = tid >> 6;
    int d4 = tid * 4;
    float u0 = 0.f, u1 = 0.f, u2 = 0.f, u3 = 0.f;
    float v0 = 0.f, v1 = 0.f, v2 = 0.f, v3 = 0.f;
    const float om = 1.f - ALPHA;
    for (int t = ts; t < t0; ++t) {            // warm-up (no output)
        size_t base = ((size_t)b * S_ + t) * D_ + d4;
        ushort4 q4 = *(const ushort4*)(qh + base);
        ushort4 k4 = *(const ushort4*)(kh + base);
        u0 = om * u0 + bf2f(q4.x); u1 = om * u1 + bf2f(q4.y);
        u2 = om * u2 + bf2f(q4.z); u3 = om * u3 + bf2f(q4.w);
        v0 = om * v0 + bf2f(k4.x); v1 = om * v1 + bf2f(k4.y);
        v2 = om * v2 + bf2f(k4.z); v3 = om * v3 + bf2f(k4.w);
    }
    for (int t = t0; t < t0 + TB; ++t) {       // output region
        size_t base = ((size_t)b * S_ + t) * D_ + d4;
        ushort4 q4 = *(const ushort4*)(qh + base);
        ushort4 k4 = *(const ushort4*)(kh + base);
        float4 x4 = *(const float4*)(vv + base);
        u0 = om * u0 + bf2f(q4.x); u1 = om * u1 + bf2f(q4.y);
        u2 = om * u2 + bf2f(q4.z); u3 = om * u3 + bf2f(q4.w);
        v0 = om * v0 + bf2f(k4.x); v1 = om * v1 + bf2f(k4.y);
        v2 = om * v2 + bf2f(k4.z); v3 = om * v3 + bf2f(k4.w);
        float uu = u0 * u0 + u1 * u1 + u2 * u2 + u3 * u3;
        float sd = v0 * x4.x + v1 * x4.y + v2 * x4.z + v3 * x4.w;
#pragma unroll
        for (int off = 32; off > 0; off >>= 1) {
            uu += __shfl_xor(uu, off, 64);
            sd += __shfl_xor(sd, off, 64);
        }
        if (lane == 0) {
            sm[(t - t0) * 8 + wave * 2 + 0] = uu;
            sm[(t - t0) * 8 + wave * 2 + 1] = sd;
        }
        ushort4 us;
        us.x = f2bf(u0); us.y = f2bf(u1); us.z = f2bf(u2); us.w = f2bf(u3);
        *(ushort4*)(Ub + base) = us;
    }
    __syncthreads();
    if (tid < TB) {
        float uu = sm[tid * 8 + 0] + sm[tid * 8 + 2] + sm[tid * 8 + 4] + sm[tid * 8 + 6];
        float sd = sm[tid * 8 + 1] + sm[tid * 8 + 3] + sm[tid * 8 + 5] + sm[tid * 8 + 7];
        float nrm = RFAC * fabsf(sd) * sqrtf(uu);
        float n = fmaxf(nrm, 1e-6f);
        coef[b * S_ + t0 + tid] = GAMMA * RFAC * sd / (1.f + BETA * (n - 1.f));
    }
}

// ---------------------------------------------------------------------------
// Kernel 4: out[m,n] = x[m,n] + coef[m] * sum_d U[m,d] * W[n,d]
// 256x256 tile, BK=64, 8 waves (2Mx4N), double-buffered LDS (128 KB),
// 4 quadrant-phases per K-tile: {ds_read | stage half-tile | s_barrier |
// lgkmcnt(0) | setprio(1) 16xMFMA setprio(0) | s_barrier}; vmcnt drained
// ONCE per K-tile (at the __syncthreads tile boundary, after the MFMAs).
#define BM 256
#define BN 256
#define BK 64
#define NT (D_ / BK)   // 16 K-tiles

__global__ __launch_bounds__(512, 2) void gemm_k(const unsigned short* __restrict__ A,   // M x K bf16
                                                 const unsigned short* __restrict__ Bw,  // N x K bf16
                                                 const float* __restrict__ coef,
                                                 const float* __restrict__ x,
                                                 float* __restrict__ out) {
    const int N = D_, K = D_;
    __shared__ unsigned short lds[2 * 2 * BM * BK];   // [buf][A|B], 128 KiB
    int bid = blockIdx.x;
    int swz = (bid & 7) * 32 + (bid >> 3);   // XCD-aware, 256 % 8 == 0 (bijective)
    int tm = swz >> 2, tn = swz & 3;         // N/BN = 4
    int m0 = tm * BM, n0 = tn * BN;
    int tid = threadIdx.x;
    int lane = tid & 63;
    int wid = tid >> 6;
    int wm = wid >> 2, wn = wid & 3;         // 2x4 wave grid; wave tile 128x64
    int lr = lane & 15, lg = lane >> 4;

    f32x4_t acc[8][4];
#pragma unroll
    for (int i = 0; i < 8; ++i)
#pragma unroll
        for (int j = 0; j < 4; ++j)
            acc[i][j] = (f32x4_t){0.f, 0.f, 0.f, 0.f};

    // stage half-tile h (0,1 = A rows 0-127/128-255; 2,3 = B same) of K-tile kt
    // LDS dest linear in lane (m104 rule); source pre-swizzled (rule 21).
#define STAGE_HALF(buf, kt, h)                                                        \
    {                                                                                 \
        int isB = (h) >> 1;                                                           \
        const unsigned short* Gp =                                                    \
            (isB ? Bw + (size_t)n0 * K : A + (size_t)m0 * K) + (size_t)(kt) * BK;     \
        unsigned short* Lp = lds + (buf) * 32768 + isB * 16384;                       \
        _Pragma("unroll")                                                             \
        for (int i = 0; i < 2; ++i) {                                                 \
            int c = i * 512 + tid;            /* 0..1023 16B chunks of the half */    \
            int row = ((h) & 1) * 128 + (c >> 3);                                     \
            int cl = c & 7;                                                           \
            int gc = cl ^ (row & 7);          /* pre-swizzled global chunk */         \
            __builtin_amdgcn_global_load_lds(                                         \
                (const __attribute__((address_space(1))) void*)(Gp + (size_t)row * K + gc * 8), \
                (__attribute__((address_space(3))) void*)((char*)Lp + (((((h)&1)*128 + (c>>3)) * 8 + cl) * 16)), \
                16, 0, 0);                                                            \
        }                                                                             \
    }

    // prologue: fully stage K-tile 0 into buf 0
    STAGE_HALF(0, 0, 0); STAGE_HALF(0, 0, 1); STAGE_HALF(0, 0, 2); STAGE_HALF(0, 0, 3);
    __syncthreads();

    for (int t = 0; t < NT; ++t) {
        const unsigned short* La = lds + (t & 1) * 32768;
        const unsigned short* Lb = La + 16384;
        int nb = (t + 1) & 1;
        bool more = (t + 1 < NT);
        bf16x8_t bfrag[4][2];
#pragma unroll
        for (int p = 0; p < 4; ++p) {
            if (p == 0) {
#pragma unroll
                for (int ni = 0; ni < 4; ++ni)
#pragma unroll
                    for (int kk = 0; kk < 2; ++kk) {
                        int row = wn * 64 + ni * 16 + lr;
                        int ch = (kk * 4 + lg) ^ (row & 7);
                        bfrag[ni][kk] = *(const bf16x8_t*)(Lb + (row * 8 + ch) * 8);
                    }
            }
            bf16x8_t afrag[2][2];
#pragma unroll
            for (int qq = 0; qq < 2; ++qq)
#pragma unroll
                for (int kk = 0; kk < 2; ++kk) {
                    int row = wm * 128 + p * 32 + qq * 16 + lr;
                    int ch = (kk * 4 + lg) ^ (row & 7);
                    afrag[qq][kk] = *(const bf16x8_t*)(La + (row * 8 + ch) * 8);
                }
            if (more) STAGE_HALF(nb, t + 1, p);          // 2 loads, stay in flight
            __builtin_amdgcn_s_barrier();                // lockstep (no vm drain)
            asm volatile("s_waitcnt lgkmcnt(0)" ::: "memory");
            __builtin_amdgcn_sched_barrier(0);
            __builtin_amdgcn_s_setprio(1);
#pragma unroll
            for (int qq = 0; qq < 2; ++qq)
#pragma unroll
                for (int ni = 0; ni < 4; ++ni)
#pragma unroll
                    for (int kk = 0; kk < 2; ++kk)
                        acc[p * 2 + qq][ni] = __builtin_amdgcn_mfma_f32_16x16x32_bf16(
                            afrag[qq][kk], bfrag[ni][kk], acc[p * 2 + qq][ni], 0, 0, 0);
            __builtin_amdgcn_s_setprio(0);
            if (p < 3) __builtin_amdgcn_s_barrier();     // lockstep (no vm drain)
        }
        __syncthreads();   // ONE vmcnt drain per K-tile: next tile's 8 loads landed
    }
#undef STAGE_HALF

    // Epilogue: C/D layout col = lane&15, row = (lane>>4)*4 + reg
#pragma unroll
    for (int mi = 0; mi < 8; ++mi) {
#pragma unroll
        for (int i = 0; i < 4; ++i) {
            int m = m0 + wm * 128 + mi * 16 + lg * 4 + i;
            float cf = coef[m];
#pragma unroll
            for (int ni = 0; ni < 4; ++ni) {
                int n = n0 + wn * 64 + ni * 16 + lr;
                size_t idx = (size_t)m * N + n;
                out[idx] = x[idx] + cf * acc[mi][ni][i];
            }
        }
    }
}

// ---------------------------------------------------------------------------
extern "C" void kernel_launch(void* const* d_in, const int* in_sizes, int n_in,
                              void* d_out, int out_size, void* d_ws, size_t ws_size,
                              hipStream_t stream) {
    const float* x  = (const float*)d_in[0];
    const float* q  = (const float*)d_in[1];
    const float* k  = (const float*)d_in[2];
    const float* vv = (const float*)d_in[3];
    const float* W  = (const float*)d_in[4];
    float* out = (float*)d_out;

    const size_t M = (size_t)B_ * S_;           // 16384
    char* ws = (char*)d_ws;
    unsigned short* Ub = (unsigned short*)ws;                      // 32MB
    unsigned short* Wb = (unsigned short*)(ws + M * D_ * 2);       // 2MB
    float* coef = (float*)(ws + M * D_ * 2 + (size_t)D_ * D_ * 2);
    size_t needed = M * D_ * 2 + (size_t)D_ * D_ * 2 + M * 4;
    if (ws_size < needed) return;  // fail visibly (output stays poisoned)

    // qh/kh scratch lives in d_out (64MB, dead before gemm writes out)
    unsigned short* qh = (unsigned short*)d_out;
    unsigned short* kh = qh + M * D_;

    normalize_k<<<dim3(M / 4), dim3(256), 0, stream>>>(q, k, qh, kh);
    wconv_k<<<dim3((D_ * D_) / 1024), dim3(256), 0, stream>>>(W, Wb);
    ema_coef_k<<<dim3(B_ * (S_ / TB)), dim3(256), 0, stream>>>(qh, kh, vv, Ub, coef);
    gemm_k<<<dim3((M / BM) * (D_ / BN)), dim3(512), 0, stream>>>(Ub, Wb, coef, x, out);
}

// Round 4
// 126.765 us; speedup vs baseline: 1.3877x; 1.3877x over previous
//
#include <hip/hip_runtime.h>
#include <hip/hip_bf16.h>
#include <cstdint>
#include <cstddef>

// Problem constants
#define B_ 8
#define S_ 2048
#define D_ 1024
#define RFAC 32.0f
#define ALPHA 0.2f
#define BETA 0.1f
#define GAMMA 0.1f
// EMA truncation window: 0.8^32 ~ 8e-4 ~ bf16 noise floor (threshold 0.108)
#define KW 32
#define TB 64
#define PF_ 8   // ema prefetch pipeline depth (static ring, fully unrolled)

typedef float f32x4_t __attribute__((ext_vector_type(4)));
typedef short bf16x8_t __attribute__((ext_vector_type(8)));

__device__ __forceinline__ unsigned short f2bf(float f) {
    unsigned u = __float_as_uint(f);
    u = (u + 0x7fffu + ((u >> 16) & 1u)) >> 16;
    return (unsigned short)u;
}
__device__ __forceinline__ float bf2f(unsigned short h) {
    return __uint_as_float(((unsigned)h) << 16);
}

// ---------------------------------------------------------------------------
// Kernel 1: per-row normalize, pre-scaled by ALPHA, output bf16.
__global__ __launch_bounds__(256) void normalize_k(const float* __restrict__ q,
                                                   const float* __restrict__ k,
                                                   unsigned short* __restrict__ qh,
                                                   unsigned short* __restrict__ kh) {
    int row  = blockIdx.x * 4 + (threadIdx.x >> 6);
    int lane = threadIdx.x & 63;
    const float4* qr = (const float4*)(q + (size_t)row * D_);
    const float4* kr = (const float4*)(k + (size_t)row * D_);
    float4 qa[4], ka[4];
    float sq = 0.f, sk = 0.f;
#pragma unroll
    for (int j = 0; j < 4; ++j) {
        qa[j] = qr[lane + 64 * j];
        ka[j] = kr[lane + 64 * j];
        sq += qa[j].x * qa[j].x + qa[j].y * qa[j].y + qa[j].z * qa[j].z + qa[j].w * qa[j].w;
        sk += ka[j].x * ka[j].x + ka[j].y * ka[j].y + ka[j].z * ka[j].z + ka[j].w * ka[j].w;
    }
#pragma unroll
    for (int off = 32; off > 0; off >>= 1) {
        sq += __shfl_xor(sq, off, 64);
        sk += __shfl_xor(sk, off, 64);
    }
    float rq = ALPHA / (sqrtf(sq) + 1e-6f);
    float rk = ALPHA / (sqrtf(sk) + 1e-6f);
    unsigned short* qo = qh + (size_t)row * D_;
    unsigned short* ko = kh + (size_t)row * D_;
#pragma unroll
    for (int j = 0; j < 4; ++j) {
        ushort4 oq, ok;
        oq.x = f2bf(qa[j].x * rq); oq.y = f2bf(qa[j].y * rq);
        oq.z = f2bf(qa[j].z * rq); oq.w = f2bf(qa[j].w * rq);
        ok.x = f2bf(ka[j].x * rk); ok.y = f2bf(ka[j].y * rk);
        ok.z = f2bf(ka[j].z * rk); ok.w = f2bf(ka[j].w * rk);
        ((ushort4*)qo)[lane + 64 * j] = oq;
        ((ushort4*)ko)[lane + 64 * j] = ok;
    }
}

// ---------------------------------------------------------------------------
// Kernel 2: W -> bf16 convert.
__global__ __launch_bounds__(256) void wconv_k(const float* __restrict__ W,
                                               unsigned short* __restrict__ Wb) {
    int i = blockIdx.x * 256 + threadIdx.x;
    float4 w = ((const float4*)W)[i];
    ushort4 o;
    o.x = f2bf(w.x); o.y = f2bf(w.y); o.z = f2bf(w.z); o.w = f2bf(w.w);
    ((ushort4*)Wb)[i] = o;
}

// ---------------------------------------------------------------------------
// Kernel 3: fused windowed EMA + coef, software-pipelined (depth PF_=8).
// Block = (b, 64-step chunk), 256 thr x 4 d's of u,v state in registers.
// Prefetch ring pq/pk/pv is statically indexed (full unroll) so it stays in
// VGPRs (rule #20); loads for t+8 are issued while consuming t, giving
// ~64KB in-flight per CU (vs ~8KB before) to hide HBM latency at 4 waves/CU.
__global__ __launch_bounds__(256) void ema_coef_k(const unsigned short* __restrict__ qh,
                                                  const unsigned short* __restrict__ kh,
                                                  const float* __restrict__ vv,
                                                  unsigned short* __restrict__ Ub,
                                                  float* __restrict__ coef) {
    __shared__ float sm[TB * 8];   // [t][wave*2 + {uu,sd}]
    const int chunks = S_ / TB;
    int b  = blockIdx.x / chunks;
    int t0 = (blockIdx.x % chunks) * TB;
    int ts = t0 - KW; if (ts < 0) ts = 0;
    int tid = threadIdx.x;
    int lane = tid & 63, wave = tid >> 6;
    size_t bbase = (size_t)b * S_ * D_ + tid * 4;
    const unsigned short* qp = qh + bbase;
    const unsigned short* kp = kh + bbase;
    const float* vp = vv + bbase;
    unsigned short* up = Ub + bbase;

    ushort4 pq[PF_], pk[PF_];
    float4 pv[PF_];
#pragma unroll
    for (int j = 0; j < PF_; ++j) {
        size_t o = (size_t)(ts + j) * D_;
        pq[j] = *(const ushort4*)(qp + o);
        pk[j] = *(const ushort4*)(kp + o);
        if (ts + j >= t0) pv[j] = *(const float4*)(vp + o);
    }
    float u0 = 0.f, u1 = 0.f, u2 = 0.f, u3 = 0.f;
    float v0 = 0.f, v1 = 0.f, v2 = 0.f, v3 = 0.f;
    const float om = 1.f - ALPHA;
    const int NI = t0 + TB - ts;       // 64 (chunk 0) or 96; both % 8 == 0
    const int tend = t0 + TB;
    for (int g = 0; g < NI; g += PF_) {
#pragma unroll
        for (int j = 0; j < PF_; ++j) {
            int t = ts + g + j;
            u0 = om * u0 + bf2f(pq[j].x); u1 = om * u1 + bf2f(pq[j].y);
            u2 = om * u2 + bf2f(pq[j].z); u3 = om * u3 + bf2f(pq[j].w);
            v0 = om * v0 + bf2f(pk[j].x); v1 = om * v1 + bf2f(pk[j].y);
            v2 = om * v2 + bf2f(pk[j].z); v3 = om * v3 + bf2f(pk[j].w);
            if (t >= t0) {               // wave-uniform branch
                float uu = u0 * u0 + u1 * u1 + u2 * u2 + u3 * u3;
                float sd = v0 * pv[j].x + v1 * pv[j].y + v2 * pv[j].z + v3 * pv[j].w;
#pragma unroll
                for (int off = 32; off > 0; off >>= 1) {
                    uu += __shfl_xor(uu, off, 64);
                    sd += __shfl_xor(sd, off, 64);
                }
                if (lane == 0) {
                    sm[(t - t0) * 8 + wave * 2 + 0] = uu;
                    sm[(t - t0) * 8 + wave * 2 + 1] = sd;
                }
                ushort4 us;
                us.x = f2bf(u0); us.y = f2bf(u1); us.z = f2bf(u2); us.w = f2bf(u3);
                *(ushort4*)(up + (size_t)t * D_) = us;
            }
            // prefetch t+PF_ into slot j (clamped; duplicate loads harmless)
            int tf = t + PF_;
            int tc = tf < tend ? tf : tend - 1;
            size_t o2 = (size_t)tc * D_;
            pq[j] = *(const ushort4*)(qp + o2);
            pk[j] = *(const ushort4*)(kp + o2);
            if (tf >= t0) pv[j] = *(const float4*)(vp + o2);
        }
    }
    __syncthreads();
    if (tid < TB) {
        float uu = sm[tid * 8 + 0] + sm[tid * 8 + 2] + sm[tid * 8 + 4] + sm[tid * 8 + 6];
        float sd = sm[tid * 8 + 1] + sm[tid * 8 + 3] + sm[tid * 8 + 5] + sm[tid * 8 + 7];
        float nrm = RFAC * fabsf(sd) * sqrtf(uu);
        float n = fmaxf(nrm, 1e-6f);
        coef[b * S_ + t0 + tid] = GAMMA * RFAC * sd / (1.f + BETA * (n - 1.f));
    }
}

// ---------------------------------------------------------------------------
// Kernel 4: out[m,n] = x[m,n] + coef[m] * sum_d U[m,d] * W[n,d]
// 256x256 tile, BK=64, 8 waves (2Mx4N), double-buffered LDS (128 KB),
// 4 quadrant-phases per K-tile; vmcnt drained ONCE per K-tile.
#define BM 256
#define BN 256
#define BK 64
#define NT (D_ / BK)   // 16 K-tiles

__global__ __launch_bounds__(512, 2) void gemm_k(const unsigned short* __restrict__ A,   // M x K bf16
                                                 const unsigned short* __restrict__ Bw,  // N x K bf16
                                                 const float* __restrict__ coef,
                                                 const float* __restrict__ x,
                                                 float* __restrict__ out) {
    const int N = D_, K = D_;
    __shared__ unsigned short lds[2 * 2 * BM * BK];   // [buf][A|B], 128 KiB
    int bid = blockIdx.x;
    int swz = (bid & 7) * 32 + (bid >> 3);   // XCD-aware, 256 % 8 == 0 (bijective)
    int tm = swz >> 2, tn = swz & 3;         // N/BN = 4
    int m0 = tm * BM, n0 = tn * BN;
    int tid = threadIdx.x;
    int lane = tid & 63;
    int wid = tid >> 6;
    int wm = wid >> 2, wn = wid & 3;         // 2x4 wave grid; wave tile 128x64
    int lr = lane & 15, lg = lane >> 4;

    f32x4_t acc[8][4];
#pragma unroll
    for (int i = 0; i < 8; ++i)
#pragma unroll
        for (int j = 0; j < 4; ++j)
            acc[i][j] = (f32x4_t){0.f, 0.f, 0.f, 0.f};

#define STAGE_HALF(buf, kt, h)                                                        \
    {                                                                                 \
        int isB = (h) >> 1;                                                           \
        const unsigned short* Gp =                                                    \
            (isB ? Bw + (size_t)n0 * K : A + (size_t)m0 * K) + (size_t)(kt) * BK;     \
        unsigned short* Lp = lds + (buf) * 32768 + isB * 16384;                       \
        _Pragma("unroll")                                                             \
        for (int i = 0; i < 2; ++i) {                                                 \
            int c = i * 512 + tid;            /* 0..1023 16B chunks of the half */    \
            int row = ((h) & 1) * 128 + (c >> 3);                                     \
            int cl = c & 7;                                                           \
            int gc = cl ^ (row & 7);          /* pre-swizzled global chunk */         \
            __builtin_amdgcn_global_load_lds(                                         \
                (const __attribute__((address_space(1))) void*)(Gp + (size_t)row * K + gc * 8), \
                (__attribute__((address_space(3))) void*)((char*)Lp + (((((h)&1)*128 + (c>>3)) * 8 + cl) * 16)), \
                16, 0, 0);                                                            \
        }                                                                             \
    }

    STAGE_HALF(0, 0, 0); STAGE_HALF(0, 0, 1); STAGE_HALF(0, 0, 2); STAGE_HALF(0, 0, 3);
    __syncthreads();

    for (int t = 0; t < NT; ++t) {
        const unsigned short* La = lds + (t & 1) * 32768;
        const unsigned short* Lb = La + 16384;
        int nb = (t + 1) & 1;
        bool more = (t + 1 < NT);
        bf16x8_t bfrag[4][2];
#pragma unroll
        for (int p = 0; p < 4; ++p) {
            if (p == 0) {
#pragma unroll
                for (int ni = 0; ni < 4; ++ni)
#pragma unroll
                    for (int kk = 0; kk < 2; ++kk) {
                        int row = wn * 64 + ni * 16 + lr;
                        int ch = (kk * 4 + lg) ^ (row & 7);
                        bfrag[ni][kk] = *(const bf16x8_t*)(Lb + (row * 8 + ch) * 8);
                    }
            }
            bf16x8_t afrag[2][2];
#pragma unroll
            for (int qq = 0; qq < 2; ++qq)
#pragma unroll
                for (int kk = 0; kk < 2; ++kk) {
                    int row = wm * 128 + p * 32 + qq * 16 + lr;
                    int ch = (kk * 4 + lg) ^ (row & 7);
                    afrag[qq][kk] = *(const bf16x8_t*)(La + (row * 8 + ch) * 8);
                }
            if (more) STAGE_HALF(nb, t + 1, p);          // 2 loads, stay in flight
            __builtin_amdgcn_s_barrier();                // lockstep (no vm drain)
            asm volatile("s_waitcnt lgkmcnt(0)" ::: "memory");
            __builtin_amdgcn_sched_barrier(0);
            __builtin_amdgcn_s_setprio(1);
#pragma unroll
            for (int qq = 0; qq < 2; ++qq)
#pragma unroll
                for (int ni = 0; ni < 4; ++ni)
#pragma unroll
                    for (int kk = 0; kk < 2; ++kk)
                        acc[p * 2 + qq][ni] = __builtin_amdgcn_mfma_f32_16x16x32_bf16(
                            afrag[qq][kk], bfrag[ni][kk], acc[p * 2 + qq][ni], 0, 0, 0);
            __builtin_amdgcn_s_setprio(0);
            if (p < 3) __builtin_amdgcn_s_barrier();     // lockstep (no vm drain)
        }
        __syncthreads();   // ONE vmcnt drain per K-tile
    }
#undef STAGE_HALF

    // Epilogue: C/D layout col = lane&15, row = (lane>>4)*4 + reg
#pragma unroll
    for (int mi = 0; mi < 8; ++mi) {
#pragma unroll
        for (int i = 0; i < 4; ++i) {
            int m = m0 + wm * 128 + mi * 16 + lg * 4 + i;
            float cf = coef[m];
#pragma unroll
            for (int ni = 0; ni < 4; ++ni) {
                int n = n0 + wn * 64 + ni * 16 + lr;
                size_t idx = (size_t)m * N + n;
                out[idx] = x[idx] + cf * acc[mi][ni][i];
            }
        }
    }
}

// ---------------------------------------------------------------------------
extern "C" void kernel_launch(void* const* d_in, const int* in_sizes, int n_in,
                              void* d_out, int out_size, void* d_ws, size_t ws_size,
                              hipStream_t stream) {
    const float* x  = (const float*)d_in[0];
    const float* q  = (const float*)d_in[1];
    const float* k  = (const float*)d_in[2];
    const float* vv = (const float*)d_in[3];
    const float* W  = (const float*)d_in[4];
    float* out = (float*)d_out;

    const size_t M = (size_t)B_ * S_;           // 16384
    char* ws = (char*)d_ws;
    unsigned short* Ub = (unsigned short*)ws;                      // 32MB
    unsigned short* Wb = (unsigned short*)(ws + M * D_ * 2);       // 2MB
    float* coef = (float*)(ws + M * D_ * 2 + (size_t)D_ * D_ * 2);
    size_t needed = M * D_ * 2 + (size_t)D_ * D_ * 2 + M * 4;
    if (ws_size < needed) return;  // fail visibly (output stays poisoned)

    // qh/kh scratch lives in d_out (64MB, dead before gemm writes out)
    unsigned short* qh = (unsigned short*)d_out;
    unsigned short* kh = qh + M * D_;

    normalize_k<<<dim3(M / 4), dim3(256), 0, stream>>>(q, k, qh, kh);
    wconv_k<<<dim3((D_ * D_) / 1024), dim3(256), 0, stream>>>(W, Wb);
    ema_coef_k<<<dim3(B_ * (S_ / TB)), dim3(256), 0, stream>>>(qh, kh, vv, Ub, coef);
    gemm_k<<<dim3((M / BM) * (D_ / BN)), dim3(512), 0, stream>>>(Ub, Wb, coef, x, out);
}